// Round 2
// baseline (921.737 us; speedup 1.0000x reference)
//
#include <hip/hip_runtime.h>

#define NB   128
#define NIN  1024
#define NH   1024
#define BETAF 0.95f
#define PIF  3.14159265358979f
#define TOT  (NB*NH*NIN)   // 2^27 dW elements

// d_out flat layout (elements), return order:
// spk(B*NH), mem_new(B*NH), loss_mean(1), spk_trace_new(B*NH),
// inp_trace_new(B*NIN), current_dW_new(B*NH*NIN), sample_loss_new(B)
#define OFF_SPK    0
#define OFF_MEM    (NB*NH)
#define OFF_LOSS   (2*NB*NH)
#define OFF_SPKTR  (2*NB*NH + 1)
#define OFF_INPTR  (3*NB*NH + 1)
#define OFF_DW     (3*NB*NH + NB*NIN + 1)
#define OFF_SLOSS  (OFF_DW + (size_t)NB*NH*NIN)

typedef float f4 __attribute__((ext_vector_type(4)));

// ---------------------------------------------------------------------------
// Kernel 1: inp_trace_new = beta*inp_trace + inp ; init loss accumulator
// ---------------------------------------------------------------------------
__global__ __launch_bounds__(256) void k_trace(
    const float* __restrict__ inp, const float* __restrict__ inp_trace,
    float* __restrict__ out)
{
    int t = blockIdx.x * 256 + threadIdx.x;
    out[OFF_INPTR + t] = BETAF * inp_trace[t] + inp[t];
    if (t == 0)
        out[OFF_LOSS] = 0.0f;
}

// ---------------------------------------------------------------------------
// Kernel 2: cur = inp @ W^T, leaky step, spk, spk_trace.
// One wave per (b,h); float4 loads (8 VMEM instr/wave instead of 32);
// fp64 accumulation to keep threshold crossings faithful to the reference.
// No atomics (the round-0 421 us was 65536 same-line device atomics).
// ---------------------------------------------------------------------------
__global__ __launch_bounds__(256) void k_leaky(
    const float* __restrict__ inp, const float* __restrict__ W,
    const float* __restrict__ mem, const float* __restrict__ spk_trace,
    float* __restrict__ out)
{
    const int b    = blockIdx.y;
    const int wave = threadIdx.x >> 6;
    const int lane = threadIdx.x & 63;
    const int h    = blockIdx.x * 4 + wave;

    const float* ir = inp + b * NIN;
    const float* wr = W   + h * NIN;

    double acc = 0.0;
    #pragma unroll
    for (int i = 0; i < NIN; i += 256) {
        f4 a = *(const f4*)(ir + i + (lane << 2));
        f4 w = *(const f4*)(wr + i + (lane << 2));
        acc = fma((double)a.x, (double)w.x, acc);
        acc = fma((double)a.y, (double)w.y, acc);
        acc = fma((double)a.z, (double)w.z, acc);
        acc = fma((double)a.w, (double)w.w, acc);
    }

    #pragma unroll
    for (int off = 32; off > 0; off >>= 1)
        acc += __shfl_down(acc, off, 64);

    if (lane == 0) {
        const int idx = b * NH + h;
        float cur = (float)acc;
        float m   = mem[idx];
        float mn  = BETAF * m + cur - (m > 1.0f ? 1.0f : 0.0f);
        float spk = (mn > 1.0f) ? 1.0f : 0.0f;
        out[OFF_SPK   + idx] = spk;
        out[OFF_MEM   + idx] = mn;
        out[OFF_SPKTR + idx] = spk_trace[idx] + spk * 0.01f;
    }
}

// ---------------------------------------------------------------------------
// Kernel 2b: per-sample loss. One block per b; 128 total atomics to the mean.
// ---------------------------------------------------------------------------
__global__ __launch_bounds__(256) void k_loss(
    const float* __restrict__ pst, const float* __restrict__ sample_loss,
    const int* __restrict__ bf_p, float* __restrict__ out)
{
    const int b = blockIdx.x;
    const int t = threadIdx.x;
    const float* spk = out + OFF_SPK + b * NH;
    const float* pr  = pst + b * NH;

    float s = 0.0f;
    #pragma unroll
    for (int k = 0; k < 4; ++k) {
        int h = t + k * 256;
        s += spk[h] * pr[h];
    }
    #pragma unroll
    for (int off = 32; off > 0; off >>= 1)
        s += __shfl_down(s, off, 64);

    __shared__ float sl[4];
    if ((t & 63) == 0) sl[t >> 6] = s;
    __syncthreads();
    if (t == 0) {
        float bf = (float)(*bf_p);
        float c  = -bf * (sl[0] + sl[1] + sl[2] + sl[3]);
        out[OFF_SLOSS + b] = sample_loss[b] + c;
        atomicAdd(&out[OFF_LOSS], c * (1.0f / NB));
    }
}

// ---------------------------------------------------------------------------
// Kernel 3: dW_new[e] = dW[e] + p(bh(e)) * itn(b(e), i(e))   for e in [0,2^27)
// ALIGNED-STORE version: od = out+OFF_DW sits at element offset ≡1 (mod 4),
// so thread t owns e = 4t+3..4t+6  ->  od+e is 16B-aligned: NT dwordx4 store
// streams at fill-kernel rate. The misalignment moves to the dW LOAD (plain,
// absorbed by L1/L2 line splits; same HBM lines fetched).
// Row-crossing vectors (i0==1023, one lane per 4th wave) blend p of bh and
// bh+1. Elements {0,1,2} and the final scalar are special-cased.
// ---------------------------------------------------------------------------
__global__ __launch_bounds__(256) void k_dw(
    const float* __restrict__ dW, const float* __restrict__ pst,
    const int* __restrict__ bf_p, float* __restrict__ out)
{
    const float* __restrict__ itn  = out + OFF_INPTR;
    const float* __restrict__ memn = out + OFF_MEM;
    float* __restrict__ od = out + OFF_DW;

    const int t  = blockIdx.x * 256 + threadIdx.x;   // [0, 2^25)
    const int e  = (t << 2) + 3;                     // out element, ≡3 mod 4
    const float bf = (float)(*bf_p);

    const int bh0 = e >> 10;                         // uniform per wave (mostly)
    float x0  = memn[bh0] - 1.0f;
    float px0 = PIF * x0;
    float p0  = bf * pst[bh0] / (PIF * (1.0f + px0 * px0));
    const float* it0 = itn + ((bh0 >> 10) << 10);    // row b0 of inp_trace_new
    const int i0  = e & (NIN - 1);                   // ≡3 mod 4

    f4 d;
    const bool full = (e + 3 < TOT);                 // false only for last thread
    if (full) {
        d = *(const f4*)(dW + e);                    // dword-aligned dwordx4 (HW-legal)
    } else {
        d.x = dW[e]; d.y = 0.0f; d.z = 0.0f; d.w = 0.0f;
    }

    f4 r;
    if (i0 != NIN - 1) {                             // no row crossing
        r.x = d.x + p0 * it0[i0];
        r.y = d.y + p0 * it0[i0 + 1];
        r.z = d.z + p0 * it0[i0 + 2];
        r.w = d.w + p0 * it0[i0 + 3];
        __builtin_nontemporal_store(r, (f4*)(od + e));
    } else {
        r.x = d.x + p0 * it0[NIN - 1];
        if (full) {
            const int bh1 = bh0 + 1;
            float x1  = memn[bh1] - 1.0f;
            float px1 = PIF * x1;
            float p1  = bf * pst[bh1] / (PIF * (1.0f + px1 * px1));
            const float* it1 = itn + ((bh1 >> 10) << 10);
            r.y = d.y + p1 * it1[0];
            r.z = d.z + p1 * it1[1];
            r.w = d.w + p1 * it1[2];
            __builtin_nontemporal_store(r, (f4*)(od + e));
        } else {
            od[e] = r.x;                             // e == TOT-1
        }
    }

    if (t == 0) {                                    // elements 0..2 (bh==0 row)
        od[0] = dW[0] + p0 * it0[0];
        od[1] = dW[1] + p0 * it0[1];
        od[2] = dW[2] + p0 * it0[2];
    }
}

extern "C" void kernel_launch(void* const* d_in, const int* in_sizes, int n_in,
                              void* d_out, int out_size, void* d_ws, size_t ws_size,
                              hipStream_t stream)
{
    const float* inp        = (const float*)d_in[0];
    const float* W          = (const float*)d_in[1];
    const float* mem        = (const float*)d_in[2];
    const float* spk_trace  = (const float*)d_in[3];
    const float* inp_trace  = (const float*)d_in[4];
    const float* pst        = (const float*)d_in[5];
    const float* dW         = (const float*)d_in[6];
    const float* sloss      = (const float*)d_in[7];
    const int*   bf_p       = (const int*)  d_in[8];
    float* out = (float*)d_out;

    // 1) input trace + loss-mean init
    k_trace<<<dim3((NB * NIN) / 256), dim3(256), 0, stream>>>(inp, inp_trace, out);

    // 2) matmul + leaky step: grid (NH/4, B), 4 waves/block, no atomics
    k_leaky<<<dim3(NH / 4, NB), dim3(256), 0, stream>>>(
        inp, W, mem, spk_trace, out);

    // 2b) loss reduction: 128 blocks, 128 total atomics
    k_loss<<<dim3(NB), dim3(256), 0, stream>>>(pst, sloss, bf_p, out);

    // 3) dW streaming update: aligned NT stores, 2^25 threads * 4 elements
    k_dw<<<dim3((TOT / 4) / 256), dim3(256), 0, stream>>>(dW, pst, bf_p, out);
}